// Round 2
// baseline (296.357 us; speedup 1.0000x reference)
//
#include <hip/hip_runtime.h>

// Dtype (R1 post-mortem): inputs/outputs are FLOAT32 (reference dtype; R1 NaN
// came from reading f32 bits as bf16). Threshold is 2% relative (6.156e-2 =
// 0.02 * 3.078125), so internal bf16 MFMA compute is within budget.

typedef __attribute__((ext_vector_type(4))) float  floatx4;
typedef __attribute__((ext_vector_type(8))) short  shortx8;

__device__ __forceinline__ short f2bf(float f) {
    unsigned u = __builtin_bit_cast(unsigned, f);
    u += 0x7fffu + ((u >> 16) & 1u);   // RTNE
    return (short)(u >> 16);
}

// Load 8 consecutive f32 (32B-aligned) and pack to 8 bf16.
__device__ __forceinline__ shortx8 cvt8(const float* __restrict__ p) {
    floatx4 a = *(const floatx4*)p;
    floatx4 b = *(const floatx4*)(p + 4);
    shortx8 r;
    r[0] = f2bf(a[0]); r[1] = f2bf(a[1]); r[2] = f2bf(a[2]); r[3] = f2bf(a[3]);
    r[4] = f2bf(b[0]); r[5] = f2bf(b[1]); r[6] = f2bf(b[2]); r[7] = f2bf(b[3]);
    return r;
}

// Repack W [K,N] (row-major f32) into bf16 MFMA-B fragment order for
// mfma_f32_16x16x32_bf16: tile (nt,kt); lane l holds
// B[kt*32 + (l>>4)*8 + j][nt*16 + (l&15)], j=0..7, contiguous 16B per lane.
__global__ void repack_w(const float* __restrict__ src, short* __restrict__ dst,
                         int N, int KT) {
    int t = blockIdx.x * blockDim.x + threadIdx.x;
    int total = (N >> 4) * KT * 64;
    if (t >= total) return;
    int lane = t & 63;
    int tile = t >> 6;
    int nt = tile / KT;
    int kt = tile - nt * KT;
    int col  = nt * 16 + (lane & 15);
    int row0 = kt * 32 + (lane >> 4) * 8;
    shortx8 v;
#pragma unroll
    for (int j = 0; j < 8; ++j) v[j] = f2bf(src[(row0 + j) * N + col]);
    *(shortx8*)(dst + t * 8) = v;
}

// Fused 3-layer MLP. TM=64 tokens per block, 8 waves (512 thr).
// A-fragment: lane holds A[m=lane&15][k=(lane>>4)*8+j].
// C/D: col=lane&15, row=(lane>>4)*4+reg (m89-verified).
__global__ __launch_bounds__(512, 2) void fused_mlp(
    const float* __restrict__ content, const float* __restrict__ motion,
    const float* __restrict__ b1, const float* __restrict__ b2,
    const float* __restrict__ b3,
    const short* __restrict__ w1p, const short* __restrict__ w2p,
    const short* __restrict__ w3p, float* __restrict__ out)
{
    __shared__ short h1[64 * 264];   // 256 cols + 8 pad
    __shared__ short h2[64 * 520];   // 512 cols + 8 pad

    const int tid  = threadIdx.x;
    const int lane = tid & 63;
    const int wave = tid >> 6;
    const int mh   = wave >> 2;      // 0..1 : row half (32 rows)
    const int wq   = wave & 3;       // 0..3 : column-group slot
    const int l15  = lane & 15;
    const int q    = lane >> 4;      // 0..3
    const int m0   = blockIdx.x * 64;
    const int bidx = m0 >> 9;        // batch index (512 tokens per b)

    // ---------------- Layer 1: X[64,384] @ W1[384,256] ----------------
    {
        const int g = wq;            // 4 n-groups of 64 cols
        floatx4 acc[2][4] = {};
        const float* crow = content + bidx * 256;
#pragma unroll
        for (int kt = 0; kt < 12; ++kt) {
            const int c0 = kt * 32 + q * 8;
            shortx8 a0, a1;
            if (kt < 8) {
                a0 = cvt8(crow + c0);   // content: same for all tokens in block
                a1 = a0;
            } else {
                const int t0 = m0 + mh * 32 + l15;
                a0 = cvt8(motion + (t0     ) * 128 + (c0 - 256));
                a1 = cvt8(motion + (t0 + 16) * 128 + (c0 - 256));
            }
#pragma unroll
            for (int nt = 0; nt < 4; ++nt) {
                shortx8 bf = *(const shortx8*)(w1p + ((g * 4 + nt) * 12 + kt) * 512 + lane * 8);
                acc[0][nt] = __builtin_amdgcn_mfma_f32_16x16x32_bf16(a0, bf, acc[0][nt], 0, 0, 0);
                acc[1][nt] = __builtin_amdgcn_mfma_f32_16x16x32_bf16(a1, bf, acc[1][nt], 0, 0, 0);
            }
        }
#pragma unroll
        for (int mt = 0; mt < 2; ++mt)
#pragma unroll
        for (int nt = 0; nt < 4; ++nt) {
            const int col = (g * 4 + nt) * 16 + l15;
            const float bias = b1[col];
#pragma unroll
            for (int r = 0; r < 4; ++r) {
                const int row = mh * 32 + mt * 16 + q * 4 + r;
                float v = acc[mt][nt][r] + bias;
                v = (v >= 0.f) ? v : 0.2f * v;
                h1[row * 264 + col] = f2bf(v);
            }
        }
    }
    __syncthreads();

    // ---------------- Layer 2: h1[64,256] @ W2[256,512] ----------------
    {
        shortx8 a2[2][8];
#pragma unroll
        for (int mt = 0; mt < 2; ++mt)
#pragma unroll
        for (int kt = 0; kt < 8; ++kt)
            a2[mt][kt] = *(const shortx8*)(&h1[(mh * 32 + mt * 16 + l15) * 264 + kt * 32 + q * 8]);

#pragma unroll
        for (int gi = 0; gi < 2; ++gi) {
            const int g = wq + gi * 4;   // 8 n-groups of 64 cols
            floatx4 acc[2][4] = {};
#pragma unroll
            for (int kt = 0; kt < 8; ++kt) {
#pragma unroll
                for (int nt = 0; nt < 4; ++nt) {
                    shortx8 bf = *(const shortx8*)(w2p + ((g * 4 + nt) * 8 + kt) * 512 + lane * 8);
                    acc[0][nt] = __builtin_amdgcn_mfma_f32_16x16x32_bf16(a2[0][kt], bf, acc[0][nt], 0, 0, 0);
                    acc[1][nt] = __builtin_amdgcn_mfma_f32_16x16x32_bf16(a2[1][kt], bf, acc[1][nt], 0, 0, 0);
                }
            }
#pragma unroll
            for (int mt = 0; mt < 2; ++mt)
#pragma unroll
            for (int nt = 0; nt < 4; ++nt) {
                const int col = (g * 4 + nt) * 16 + l15;
                const float bias = b2[col];
#pragma unroll
                for (int r = 0; r < 4; ++r) {
                    const int row = mh * 32 + mt * 16 + q * 4 + r;
                    float v = acc[mt][nt][r] + bias;
                    v = (v >= 0.f) ? v : 0.2f * v;
                    h2[row * 520 + col] = f2bf(v);
                }
            }
        }
    }
    __syncthreads();

    // ---------------- Layer 3: h2[64,512] @ W3[512,1152] ----------------
#pragma unroll
    for (int gi = 0; gi < 3; ++gi) {
        const int g = wq + gi * 4;       // 12 n-groups of 96 cols
        floatx4 acc[2][6] = {};
#pragma unroll
        for (int kt = 0; kt < 16; ++kt) {
            shortx8 a0 = *(const shortx8*)(&h2[(mh * 32 +      l15) * 520 + kt * 32 + q * 8]);
            shortx8 a1 = *(const shortx8*)(&h2[(mh * 32 + 16 + l15) * 520 + kt * 32 + q * 8]);
#pragma unroll
            for (int nt = 0; nt < 6; ++nt) {
                shortx8 bf = *(const shortx8*)(w3p + ((g * 6 + nt) * 16 + kt) * 512 + lane * 8);
                acc[0][nt] = __builtin_amdgcn_mfma_f32_16x16x32_bf16(a0, bf, acc[0][nt], 0, 0, 0);
                acc[1][nt] = __builtin_amdgcn_mfma_f32_16x16x32_bf16(a1, bf, acc[1][nt], 0, 0, 0);
            }
        }
#pragma unroll
        for (int mt = 0; mt < 2; ++mt)
#pragma unroll
        for (int nt = 0; nt < 6; ++nt) {
            const int col = (g * 6 + nt) * 16 + l15;
            const float bias = b3[col];
#pragma unroll
            for (int r = 0; r < 4; ++r) {
                const int token = m0 + mh * 32 + mt * 16 + q * 4 + r;
                out[token * 1152 + col] = acc[mt][nt][r] + bias;
            }
        }
    }
}

extern "C" void kernel_launch(void* const* d_in, const int* in_sizes, int n_in,
                              void* d_out, int out_size, void* d_ws, size_t ws_size,
                              hipStream_t stream) {
    const float* content = (const float*)d_in[0];  // [64,256]
    const float* motion  = (const float*)d_in[1];  // [64,512,128]
    const float* W1 = (const float*)d_in[2];       // [384,256]
    const float* b1 = (const float*)d_in[3];
    const float* W2 = (const float*)d_in[4];       // [256,512]
    const float* b2 = (const float*)d_in[5];
    const float* W3 = (const float*)d_in[6];       // [512,1152]
    const float* b3 = (const float*)d_in[7];
    float* out = (float*)d_out;

    short* ws  = (short*)d_ws;                     // 1.64 MB repacked bf16 weights
    short* w1p = ws;                               // 16 nt * 12 kt * 512
    short* w2p = ws + 98304;                       // 32 nt *  8 kt * 512
    short* w3p = ws + 98304 + 131072;              // 72 nt * 16 kt * 512

    repack_w<<<48,  256, 0, stream>>>(W1, w1p, 256, 12);
    repack_w<<<64,  256, 0, stream>>>(W2, w2p, 512, 8);
    repack_w<<<288, 256, 0, stream>>>(W3, w3p, 1152, 16);

    fused_mlp<<<512, 512, 0, stream>>>(content, motion, b1, b2, b3,
                                       w1p, w2p, w3p, out);
}

// Round 3
// 295.589 us; speedup vs baseline: 1.0026x; 1.0026x over previous
//
#include <hip/hip_runtime.h>

// I/O: float32 (per reference). Internal compute: bf16 MFMA (2%-relative
// threshold; measured absmax 0.0156 vs 0.0615 budget in R2).
//
// R3 structure: one fused kernel, TM=64 tokens/block, 8 waves. Each wave owns
// ALL 4 m-tiles x a private column strip per layer (L1: 32 cols, L2: 64,
// L3: 144). Every weight B-fragment is read exactly once per block (no mh
// duplication) and feeds 4 MFMAs. LDS: single 66.6 KB buffer; h1 (stride 264)
// overlays the h2 (stride 520) region — h1 is dead before h2 is written.

typedef __attribute__((ext_vector_type(4))) float  floatx4;
typedef __attribute__((ext_vector_type(8))) short  shortx8;

__device__ __forceinline__ short f2bf(float f) {
    unsigned u = __builtin_bit_cast(unsigned, f);
    u += 0x7fffu + ((u >> 16) & 1u);   // RTNE
    return (short)(u >> 16);
}

__device__ __forceinline__ shortx8 cvt8(const float* __restrict__ p) {
    floatx4 a = *(const floatx4*)p;
    floatx4 b = *(const floatx4*)(p + 4);
    shortx8 r;
    r[0] = f2bf(a[0]); r[1] = f2bf(a[1]); r[2] = f2bf(a[2]); r[3] = f2bf(a[3]);
    r[4] = f2bf(b[0]); r[5] = f2bf(b[1]); r[6] = f2bf(b[2]); r[7] = f2bf(b[3]);
    return r;
}

// Single-launch repack of W1/W2/W3 (f32 row-major [K,N]) into bf16 MFMA-B
// fragment order. Tile rel=(nt*KT+kt): lane l holds
// B[kt*32+(l>>4)*8+j][nt*16+(l&15)], j=0..7, 16B contiguous per lane.
// Segment boundaries are wave-aligned (tile = t>>6) -> wave-uniform branches.
__global__ void repack_all(const float* __restrict__ W1,
                           const float* __restrict__ W2,
                           const float* __restrict__ W3,
                           short* __restrict__ ws) {
    int t = blockIdx.x * blockDim.x + threadIdx.x;
    int tile = t >> 6, lane = t & 63;
    const float* src; short* dst; int N, KT, rel;
    if (tile < 192)       { src = W1; dst = ws;                  N = 256;  KT = 12; rel = tile; }
    else if (tile < 448)  { src = W2; dst = ws + 98304;          N = 512;  KT = 8;  rel = tile - 192; }
    else if (tile < 1600) { src = W3; dst = ws + 98304 + 131072; N = 1152; KT = 16; rel = tile - 448; }
    else return;
    int nt = rel / KT, kt = rel - nt * KT;
    int col  = nt * 16 + (lane & 15);
    int row0 = kt * 32 + (lane >> 4) * 8;
    shortx8 v;
#pragma unroll
    for (int j = 0; j < 8; ++j) v[j] = f2bf(src[(row0 + j) * N + col]);
    *(shortx8*)(dst + rel * 512 + lane * 8) = v;
}

__global__ __launch_bounds__(512, 2) void fused_mlp(
    const float* __restrict__ content, const float* __restrict__ motion,
    const float* __restrict__ b1, const float* __restrict__ b2,
    const float* __restrict__ b3,
    const short* __restrict__ w1p, const short* __restrict__ w2p,
    const short* __restrict__ w3p, float* __restrict__ out)
{
    __shared__ short hbuf[64 * 520];   // h2 view: stride 520; h1 view: stride 264

    const int tid  = threadIdx.x;
    const int lane = tid & 63;
    const int w    = tid >> 6;        // wave 0..7: column-strip owner
    const int l15  = lane & 15;
    const int q    = lane >> 4;       // 0..3
    const int m0   = blockIdx.x * 64;
    const int bidx = m0 >> 9;

    // ---------------- Layer 1: X[64,384] @ W1 -> h1[64,256] ----------------
    {
        floatx4 acc[4][2] = {};
        const float* crow = content + bidx * 256;
#pragma unroll
        for (int kt = 0; kt < 12; ++kt) {
            const int c0 = kt * 32 + q * 8;
            shortx8 a[4];
            if (kt < 8) {
                a[0] = cvt8(crow + c0);   // content rows identical -> one frag for all mt
                a[1] = a[0]; a[2] = a[0]; a[3] = a[0];
            } else {
#pragma unroll
                for (int mt = 0; mt < 4; ++mt)
                    a[mt] = cvt8(motion + (m0 + mt * 16 + l15) * 128 + (c0 - 256));
            }
#pragma unroll
            for (int nt = 0; nt < 2; ++nt) {
                shortx8 bf = *(const shortx8*)(w1p + ((w * 2 + nt) * 12 + kt) * 512 + lane * 8);
#pragma unroll
                for (int mt = 0; mt < 4; ++mt)
                    acc[mt][nt] = __builtin_amdgcn_mfma_f32_16x16x32_bf16(a[mt], bf, acc[mt][nt], 0, 0, 0);
            }
        }
#pragma unroll
        for (int nt = 0; nt < 2; ++nt) {
            const int col = (w * 2 + nt) * 16 + l15;
            const float bias = b1[col];
#pragma unroll
            for (int mt = 0; mt < 4; ++mt)
#pragma unroll
            for (int r = 0; r < 4; ++r) {
                float v = acc[mt][nt][r] + bias;
                v = (v >= 0.f) ? v : 0.2f * v;
                hbuf[(mt * 16 + q * 4 + r) * 264 + col] = f2bf(v);
            }
        }
    }
    __syncthreads();

    // ---------------- Layer 2: h1[64,256] @ W2 -> h2[64,512] ----------------
    {
        floatx4 acc[4][4] = {};
#pragma unroll
        for (int kt = 0; kt < 8; ++kt) {
            shortx8 a[4];
#pragma unroll
            for (int mt = 0; mt < 4; ++mt)
                a[mt] = *(const shortx8*)(&hbuf[(mt * 16 + l15) * 264 + kt * 32 + q * 8]);
#pragma unroll
            for (int nt = 0; nt < 4; ++nt) {
                shortx8 bf = *(const shortx8*)(w2p + ((w * 4 + nt) * 8 + kt) * 512 + lane * 8);
#pragma unroll
                for (int mt = 0; mt < 4; ++mt)
                    acc[mt][nt] = __builtin_amdgcn_mfma_f32_16x16x32_bf16(a[mt], bf, acc[mt][nt], 0, 0, 0);
            }
        }
        __syncthreads();   // all h1 reads complete before h2 overwrites buffer
#pragma unroll
        for (int nt = 0; nt < 4; ++nt) {
            const int col = (w * 4 + nt) * 16 + l15;
            const float bias = b2[col];
#pragma unroll
            for (int mt = 0; mt < 4; ++mt)
#pragma unroll
            for (int r = 0; r < 4; ++r) {
                float v = acc[mt][nt][r] + bias;
                v = (v >= 0.f) ? v : 0.2f * v;
                hbuf[(mt * 16 + q * 4 + r) * 520 + col] = f2bf(v);
            }
        }
    }
    __syncthreads();

    // ---------------- Layer 3: h2[64,512] @ W3 -> out[64,1152] ----------------
    {
        floatx4 acc[4][9] = {};   // 144 VGPRs
#pragma unroll 4
        for (int kt = 0; kt < 16; ++kt) {
            shortx8 a[4];
#pragma unroll
            for (int mt = 0; mt < 4; ++mt)
                a[mt] = *(const shortx8*)(&hbuf[(mt * 16 + l15) * 520 + kt * 32 + q * 8]);
#pragma unroll
            for (int nt = 0; nt < 9; ++nt) {
                shortx8 bf = *(const shortx8*)(w3p + ((w * 9 + nt) * 16 + kt) * 512 + lane * 8);
#pragma unroll
                for (int mt = 0; mt < 4; ++mt)
                    acc[mt][nt] = __builtin_amdgcn_mfma_f32_16x16x32_bf16(a[mt], bf, acc[mt][nt], 0, 0, 0);
            }
        }
#pragma unroll
        for (int nt = 0; nt < 9; ++nt) {
            const int col = (w * 9 + nt) * 16 + l15;
            const float bias = b3[col];
#pragma unroll
            for (int mt = 0; mt < 4; ++mt)
#pragma unroll
            for (int r = 0; r < 4; ++r)
                out[(m0 + mt * 16 + q * 4 + r) * 1152 + col] = acc[mt][nt][r] + bias;
        }
    }
}

extern "C" void kernel_launch(void* const* d_in, const int* in_sizes, int n_in,
                              void* d_out, int out_size, void* d_ws, size_t ws_size,
                              hipStream_t stream) {
    const float* content = (const float*)d_in[0];  // [64,256]
    const float* motion  = (const float*)d_in[1];  // [64,512,128]
    const float* W1 = (const float*)d_in[2];       // [384,256]
    const float* b1 = (const float*)d_in[3];
    const float* W2 = (const float*)d_in[4];       // [256,512]
    const float* b2 = (const float*)d_in[5];
    const float* W3 = (const float*)d_in[6];       // [512,1152]
    const float* b3 = (const float*)d_in[7];
    float* out = (float*)d_out;

    short* ws  = (short*)d_ws;
    short* w1p = ws;                     // 192 tiles * 512 elems
    short* w2p = ws + 98304;             // 256 tiles * 512
    short* w3p = ws + 98304 + 131072;    // 1152 tiles * 512

    repack_all<<<400, 256, 0, stream>>>(W1, W2, W3, ws);
    fused_mlp<<<512, 512, 0, stream>>>(content, motion, b1, b2, b3,
                                       w1p, w2p, w3p, out);
}

// Round 4
// 224.313 us; speedup vs baseline: 1.3212x; 1.3177x over previous
//
#include <hip/hip_runtime.h>

// I/O: float32 (per reference). Internal compute: bf16 MFMA (2%-relative
// threshold; measured absmax 0.0156 vs 0.0615 budget in R2/R3).
//
// R4: occupancy fix. R3 stalled at OccupancyPercent 22% (1 block/CU) because
// L3's acc[4][9]=144 AGPRs pushed effective regs/wave to ~256 (2 waves/SIMD
// cap). Now L3 runs in 3 gi-passes of acc[4][3] (48 accs), re-reading
// A-fragments from LDS each pass, and __launch_bounds__(512,4) pins regs
// <=128 so 2 blocks/CU (4 waves/SIMD) co-reside. 512 blocks = exactly 2/CU.

typedef __attribute__((ext_vector_type(4))) float  floatx4;
typedef __attribute__((ext_vector_type(8))) short  shortx8;

__device__ __forceinline__ short f2bf(float f) {
    unsigned u = __builtin_bit_cast(unsigned, f);
    u += 0x7fffu + ((u >> 16) & 1u);   // RTNE
    return (short)(u >> 16);
}

__device__ __forceinline__ shortx8 cvt8(const float* __restrict__ p) {
    floatx4 a = *(const floatx4*)p;
    floatx4 b = *(const floatx4*)(p + 4);
    shortx8 r;
    r[0] = f2bf(a[0]); r[1] = f2bf(a[1]); r[2] = f2bf(a[2]); r[3] = f2bf(a[3]);
    r[4] = f2bf(b[0]); r[5] = f2bf(b[1]); r[6] = f2bf(b[2]); r[7] = f2bf(b[3]);
    return r;
}

// Single-launch repack of W1/W2/W3 (f32 row-major [K,N]) into bf16 MFMA-B
// fragment order. Tile rel=(nt*KT+kt): lane l holds
// B[kt*32+(l>>4)*8+j][nt*16+(l&15)], j=0..7, 16B contiguous per lane.
__global__ void repack_all(const float* __restrict__ W1,
                           const float* __restrict__ W2,
                           const float* __restrict__ W3,
                           short* __restrict__ ws) {
    int t = blockIdx.x * blockDim.x + threadIdx.x;
    int tile = t >> 6, lane = t & 63;
    const float* src; short* dst; int N, KT, rel;
    if (tile < 192)       { src = W1; dst = ws;                  N = 256;  KT = 12; rel = tile; }
    else if (tile < 448)  { src = W2; dst = ws + 98304;          N = 512;  KT = 8;  rel = tile - 192; }
    else if (tile < 1600) { src = W3; dst = ws + 98304 + 131072; N = 1152; KT = 16; rel = tile - 448; }
    else return;
    int nt = rel / KT, kt = rel - nt * KT;
    int col  = nt * 16 + (lane & 15);
    int row0 = kt * 32 + (lane >> 4) * 8;
    shortx8 v;
#pragma unroll
    for (int j = 0; j < 8; ++j) v[j] = f2bf(src[(row0 + j) * N + col]);
    *(shortx8*)(dst + rel * 512 + lane * 8) = v;
}

__global__ __launch_bounds__(512, 4) void fused_mlp(
    const float* __restrict__ content, const float* __restrict__ motion,
    const float* __restrict__ b1, const float* __restrict__ b2,
    const float* __restrict__ b3,
    const short* __restrict__ w1p, const short* __restrict__ w2p,
    const short* __restrict__ w3p, float* __restrict__ out)
{
    __shared__ short hbuf[64 * 520];   // h2 view: stride 520; h1 view: stride 264

    const int tid  = threadIdx.x;
    const int lane = tid & 63;
    const int w    = tid >> 6;        // wave 0..7: column-strip owner
    const int l15  = lane & 15;
    const int q    = lane >> 4;       // 0..3
    const int m0   = blockIdx.x * 64;
    const int bidx = m0 >> 9;

    // ---------------- Layer 1: X[64,384] @ W1 -> h1[64,256] ----------------
    {
        floatx4 acc[4][2] = {};
        const float* crow = content + bidx * 256;
#pragma unroll
        for (int kt = 0; kt < 12; ++kt) {
            const int c0 = kt * 32 + q * 8;
            shortx8 a[4];
            if (kt < 8) {
                a[0] = cvt8(crow + c0);   // content rows identical across tokens
                a[1] = a[0]; a[2] = a[0]; a[3] = a[0];
            } else {
#pragma unroll
                for (int mt = 0; mt < 4; ++mt)
                    a[mt] = cvt8(motion + (m0 + mt * 16 + l15) * 128 + (c0 - 256));
            }
#pragma unroll
            for (int nt = 0; nt < 2; ++nt) {
                shortx8 bf = *(const shortx8*)(w1p + ((w * 2 + nt) * 12 + kt) * 512 + lane * 8);
#pragma unroll
                for (int mt = 0; mt < 4; ++mt)
                    acc[mt][nt] = __builtin_amdgcn_mfma_f32_16x16x32_bf16(a[mt], bf, acc[mt][nt], 0, 0, 0);
            }
        }
#pragma unroll
        for (int nt = 0; nt < 2; ++nt) {
            const int col = (w * 2 + nt) * 16 + l15;
            const float bias = b1[col];
#pragma unroll
            for (int mt = 0; mt < 4; ++mt)
#pragma unroll
            for (int r = 0; r < 4; ++r) {
                float v = acc[mt][nt][r] + bias;
                v = (v >= 0.f) ? v : 0.2f * v;
                hbuf[(mt * 16 + q * 4 + r) * 264 + col] = f2bf(v);
            }
        }
    }
    __syncthreads();

    // ---------------- Layer 2: h1[64,256] @ W2 -> h2[64,512] ----------------
    {
        floatx4 acc[4][4] = {};
#pragma unroll
        for (int kt = 0; kt < 8; ++kt) {
            shortx8 a[4];
#pragma unroll
            for (int mt = 0; mt < 4; ++mt)
                a[mt] = *(const shortx8*)(&hbuf[(mt * 16 + l15) * 264 + kt * 32 + q * 8]);
#pragma unroll
            for (int nt = 0; nt < 4; ++nt) {
                shortx8 bf = *(const shortx8*)(w2p + ((w * 4 + nt) * 8 + kt) * 512 + lane * 8);
#pragma unroll
                for (int mt = 0; mt < 4; ++mt)
                    acc[mt][nt] = __builtin_amdgcn_mfma_f32_16x16x32_bf16(a[mt], bf, acc[mt][nt], 0, 0, 0);
            }
        }
        __syncthreads();   // all h1 reads complete before h2 overwrites buffer
#pragma unroll
        for (int nt = 0; nt < 4; ++nt) {
            const int col = (w * 4 + nt) * 16 + l15;
            const float bias = b2[col];
#pragma unroll
            for (int mt = 0; mt < 4; ++mt)
#pragma unroll
            for (int r = 0; r < 4; ++r) {
                float v = acc[mt][nt][r] + bias;
                v = (v >= 0.f) ? v : 0.2f * v;
                hbuf[(mt * 16 + q * 4 + r) * 520 + col] = f2bf(v);
            }
        }
    }
    __syncthreads();

    // -------- Layer 3: h2[64,512] @ W3 -> out[64,1152], 3 passes of 48 cols --------
#pragma unroll 1
    for (int gi = 0; gi < 3; ++gi) {
        floatx4 acc[4][3] = {};   // 48 accs: keeps regs/wave <=128 -> 4 waves/SIMD
#pragma unroll 4
        for (int kt = 0; kt < 16; ++kt) {
            shortx8 a[4];
#pragma unroll
            for (int mt = 0; mt < 4; ++mt)
                a[mt] = *(const shortx8*)(&hbuf[(mt * 16 + l15) * 520 + kt * 32 + q * 8]);
#pragma unroll
            for (int nt = 0; nt < 3; ++nt) {
                shortx8 bf = *(const shortx8*)(w3p + ((w * 9 + gi * 3 + nt) * 16 + kt) * 512 + lane * 8);
#pragma unroll
                for (int mt = 0; mt < 4; ++mt)
                    acc[mt][nt] = __builtin_amdgcn_mfma_f32_16x16x32_bf16(a[mt], bf, acc[mt][nt], 0, 0, 0);
            }
        }
#pragma unroll
        for (int nt = 0; nt < 3; ++nt) {
            const int col = (w * 9 + gi * 3 + nt) * 16 + l15;
            const float bias = b3[col];
#pragma unroll
            for (int mt = 0; mt < 4; ++mt)
#pragma unroll
            for (int r = 0; r < 4; ++r)
                out[(m0 + mt * 16 + q * 4 + r) * 1152 + col] = acc[mt][nt][r] + bias;
        }
    }
}

extern "C" void kernel_launch(void* const* d_in, const int* in_sizes, int n_in,
                              void* d_out, int out_size, void* d_ws, size_t ws_size,
                              hipStream_t stream) {
    const float* content = (const float*)d_in[0];  // [64,256]
    const float* motion  = (const float*)d_in[1];  // [64,512,128]
    const float* W1 = (const float*)d_in[2];       // [384,256]
    const float* b1 = (const float*)d_in[3];
    const float* W2 = (const float*)d_in[4];       // [256,512]
    const float* b2 = (const float*)d_in[5];
    const float* W3 = (const float*)d_in[6];       // [512,1152]
    const float* b3 = (const float*)d_in[7];
    float* out = (float*)d_out;

    short* ws  = (short*)d_ws;
    short* w1p = ws;                     // 192 tiles * 512 elems
    short* w2p = ws + 98304;             // 256 tiles * 512
    short* w3p = ws + 98304 + 131072;    // 1152 tiles * 512

    repack_all<<<400, 256, 0, stream>>>(W1, W2, W3, ws);
    fused_mlp<<<512, 512, 0, stream>>>(content, motion, b1, b2, b3,
                                       w1p, w2p, w3p, out);
}